// Round 1
// baseline (654.493 us; speedup 1.0000x reference)
//
#include <hip/hip_runtime.h>
#include <hip/hip_bf16.h>
#include <math.h>

#define S_DIM 128
#define R_DIM 256
#define M_DIM 256
#define H_DIM 8
#define C_DIM 32
#define Z_DIM 128
#define SCALE_F 0.17677669529663687f

// ws layout (floats):
//   bias : [8][256][256]      offset 0          count   524288
//   qkv  : [32768][768]       offset 524288     count 25165824
//   attn : [32768][256]       offset 25690112   count  8388608
// total 34078720 floats = 136.3 MB

// ---------------------------------------------------------------------------
// Kernel 1: bias[h][r][p] = sum_z pair[r][p][z] * bproj[z][h]
// ---------------------------------------------------------------------------
__global__ __launch_bounds__(256) void bias_kernel(
    const float* __restrict__ pair, const float* __restrict__ bproj,
    float* __restrict__ bias) {
  __shared__ float bp[Z_DIM * H_DIM];
  int t = threadIdx.x;
  for (int i = t; i < Z_DIM * H_DIM; i += 256) bp[i] = bproj[i];
  __syncthreads();
  int idx = blockIdx.x * 256 + t;  // r*256+p, 0..65535
  const float4* src = (const float4*)(pair + (size_t)idx * Z_DIM);
  float acc[H_DIM] = {0.f,0.f,0.f,0.f,0.f,0.f,0.f,0.f};
#pragma unroll
  for (int z4 = 0; z4 < Z_DIM / 4; ++z4) {
    float4 v = src[z4];
    const float* b0 = &bp[z4 * 4 * H_DIM];
#pragma unroll
    for (int h = 0; h < H_DIM; ++h) {
      acc[h] += v.x * b0[h] + v.y * b0[H_DIM + h] +
                v.z * b0[2 * H_DIM + h] + v.w * b0[3 * H_DIM + h];
    }
  }
#pragma unroll
  for (int h = 0; h < H_DIM; ++h)
    bias[(size_t)h * (R_DIM * R_DIM) + idx] = acc[h];
}

// ---------------------------------------------------------------------------
// Kernel 2: fused gate + qkv GEMM.  X[32768,256] @ {Wg[256,256] | Wqkv[256,768]}
// gate (sigmoid) -> gate_out (d_out, scratch), qkv -> qkv_out (ws)
// ---------------------------------------------------------------------------
__global__ __launch_bounds__(256) void gemm_gateqkv(
    const float* __restrict__ X, const float* __restrict__ Wg,
    const float* __restrict__ Wqkv, float* __restrict__ gate_out,
    float* __restrict__ qkv_out) {
  __shared__ float As[16][64];
  __shared__ float Bs[16][64];
  int t = threadIdx.x;
  int r0 = blockIdx.x * 64;
  int c0 = blockIdx.y * 64;  // 0..1023
  bool isGate = (c0 < M_DIM);
  const float* W = isGate ? Wg : Wqkv;
  int ldb = isGate ? M_DIM : 3 * M_DIM;
  int wc0 = isGate ? c0 : c0 - M_DIM;
  int tr = t >> 4, tc = t & 15;
  float acc[4][4] = {};
  for (int k0 = 0; k0 < M_DIM; k0 += 16) {
#pragma unroll
    for (int it = 0; it < 4; ++it) {
      int e = it * 256 + t;
      int m = e >> 4, k = e & 15;
      As[k][m] = X[(size_t)(r0 + m) * M_DIM + k0 + k];
    }
#pragma unroll
    for (int it = 0; it < 4; ++it) {
      int e = it * 256 + t;
      int k = e >> 6, n = e & 63;
      Bs[k][n] = W[(size_t)(k0 + k) * ldb + wc0 + n];
    }
    __syncthreads();
#pragma unroll
    for (int kk = 0; kk < 16; ++kk) {
      float4 a = *(const float4*)&As[kk][tr * 4];
      float4 b = *(const float4*)&Bs[kk][tc * 4];
      float av[4] = {a.x, a.y, a.z, a.w};
      float bv[4] = {b.x, b.y, b.z, b.w};
#pragma unroll
      for (int i = 0; i < 4; ++i)
#pragma unroll
        for (int j = 0; j < 4; ++j) acc[i][j] += av[i] * bv[j];
    }
    __syncthreads();
  }
#pragma unroll
  for (int i = 0; i < 4; ++i) {
    int row = r0 + tr * 4 + i;
#pragma unroll
    for (int j = 0; j < 4; ++j) {
      int col = c0 + tc * 4 + j;
      float v = acc[i][j];
      if (isGate) {
        gate_out[(size_t)row * M_DIM + col] = 1.0f / (1.0f + __expf(-v));
      } else {
        qkv_out[(size_t)row * 768 + (col - M_DIM)] = v;
      }
    }
  }
}

// ---------------------------------------------------------------------------
// Kernel 3: attention per (s,h). One row r per thread.
// attend = (sum_p exp(sim)*v)/lsum + (sum_p bias[h,r,p]*v), then * gate
// ---------------------------------------------------------------------------
__global__ __launch_bounds__(256) void attn_kernel(
    const float* __restrict__ qkv, const float* __restrict__ bias,
    const float* __restrict__ gate, float* __restrict__ attn_out) {
  int s = blockIdx.x, h = blockIdx.y;
  __shared__ float ks[R_DIM][C_DIM];
  __shared__ float vs[R_DIM][C_DIM];
  int t = threadIdx.x;
  {
    int cc4 = (t & 7) * 4;
    int p0 = t >> 3;  // 32 rows per pass
    for (int p = p0; p < R_DIM; p += 32) {
      size_t base = ((size_t)(s * R_DIM + p)) * 768 + h * 96;
      *(float4*)&ks[p][cc4] = *(const float4*)&qkv[base + 32 + cc4];
      *(float4*)&vs[p][cc4] = *(const float4*)&qkv[base + 64 + cc4];
    }
  }
  __syncthreads();
  int r = t;
  float q[C_DIM];
  {
    const float* qp = qkv + ((size_t)(s * R_DIM + r)) * 768 + h * 96;
#pragma unroll
    for (int i = 0; i < 8; ++i) {
      float4 v4 = *(const float4*)(qp + i * 4);
      q[i * 4 + 0] = v4.x; q[i * 4 + 1] = v4.y;
      q[i * 4 + 2] = v4.z; q[i * 4 + 3] = v4.w;
    }
  }
  const float* brow = bias + (size_t)h * (R_DIM * R_DIM) + (size_t)r * R_DIM;
  float lsum = 0.f;
  float uacc[C_DIM] = {};
  float bacc[C_DIM] = {};
  for (int p4 = 0; p4 < R_DIM; p4 += 4) {
    float4 bq = *(const float4*)&brow[p4];
    float bArr[4] = {bq.x, bq.y, bq.z, bq.w};
#pragma unroll
    for (int pi = 0; pi < 4; ++pi) {
      int p = p4 + pi;
      float sim = 0.f;
#pragma unroll
      for (int c4 = 0; c4 < 8; ++c4) {
        float4 kv = *(const float4*)&ks[p][c4 * 4];
        sim += q[c4 * 4 + 0] * kv.x + q[c4 * 4 + 1] * kv.y +
               q[c4 * 4 + 2] * kv.z + q[c4 * 4 + 3] * kv.w;
      }
      float e = __expf(sim * SCALE_F);
      lsum += e;
      float bb = bArr[pi];
#pragma unroll
      for (int c4 = 0; c4 < 8; ++c4) {
        float4 vv = *(const float4*)&vs[p][c4 * 4];
        uacc[c4 * 4 + 0] += e * vv.x;  uacc[c4 * 4 + 1] += e * vv.y;
        uacc[c4 * 4 + 2] += e * vv.z;  uacc[c4 * 4 + 3] += e * vv.w;
        bacc[c4 * 4 + 0] += bb * vv.x; bacc[c4 * 4 + 1] += bb * vv.y;
        bacc[c4 * 4 + 2] += bb * vv.z; bacc[c4 * 4 + 3] += bb * vv.w;
      }
    }
  }
  float inv = 1.f / lsum;
  size_t o = ((size_t)(s * R_DIM + r)) * M_DIM + h * C_DIM;
#pragma unroll
  for (int c4 = 0; c4 < 8; ++c4) {
    float4 g = *(const float4*)&gate[o + c4 * 4];
    float4 res;
    res.x = (uacc[c4 * 4 + 0] * inv + bacc[c4 * 4 + 0]) * g.x;
    res.y = (uacc[c4 * 4 + 1] * inv + bacc[c4 * 4 + 1]) * g.y;
    res.z = (uacc[c4 * 4 + 2] * inv + bacc[c4 * 4 + 2]) * g.z;
    res.w = (uacc[c4 * 4 + 3] * inv + bacc[c4 * 4 + 3]) * g.w;
    *(float4*)&attn_out[o + c4 * 4] = res;
  }
}

// ---------------------------------------------------------------------------
// Kernel 4: out = attn[32768,256] @ Wout[256,256] -> d_out
// ---------------------------------------------------------------------------
__global__ __launch_bounds__(256) void gemm_out(
    const float* __restrict__ A, const float* __restrict__ W,
    float* __restrict__ out) {
  __shared__ float As[16][64];
  __shared__ float Bs[16][64];
  int t = threadIdx.x;
  int r0 = blockIdx.x * 64;
  int c0 = blockIdx.y * 64;
  int tr = t >> 4, tc = t & 15;
  float acc[4][4] = {};
  for (int k0 = 0; k0 < M_DIM; k0 += 16) {
#pragma unroll
    for (int it = 0; it < 4; ++it) {
      int e = it * 256 + t;
      int m = e >> 4, k = e & 15;
      As[k][m] = A[(size_t)(r0 + m) * M_DIM + k0 + k];
    }
#pragma unroll
    for (int it = 0; it < 4; ++it) {
      int e = it * 256 + t;
      int k = e >> 6, n = e & 63;
      Bs[k][n] = W[(size_t)(k0 + k) * M_DIM + c0 + n];
    }
    __syncthreads();
#pragma unroll
    for (int kk = 0; kk < 16; ++kk) {
      float4 a = *(const float4*)&As[kk][tr * 4];
      float4 b = *(const float4*)&Bs[kk][tc * 4];
      float av[4] = {a.x, a.y, a.z, a.w};
      float bv[4] = {b.x, b.y, b.z, b.w};
#pragma unroll
      for (int i = 0; i < 4; ++i)
#pragma unroll
        for (int j = 0; j < 4; ++j) acc[i][j] += av[i] * bv[j];
    }
    __syncthreads();
  }
#pragma unroll
  for (int i = 0; i < 4; ++i) {
    int row = r0 + tr * 4 + i;
#pragma unroll
    for (int j = 0; j < 4; ++j) {
      int col = c0 + tc * 4 + j;
      out[(size_t)row * M_DIM + col] = acc[i][j];
    }
  }
}

// ---------------------------------------------------------------------------
extern "C" void kernel_launch(void* const* d_in, const int* in_sizes, int n_in,
                              void* d_out, int out_size, void* d_ws,
                              size_t ws_size, hipStream_t stream) {
  const float* msa  = (const float*)d_in[0];   // [1,128,256,256]
  const float* pair = (const float*)d_in[1];   // [1,256,256,128]
  const float* Wg   = (const float*)d_in[2];   // [256,256]
  const float* Wqkv = (const float*)d_in[3];   // [256,768]
  const float* Wout = (const float*)d_in[4];   // [256,256]
  const float* Bp   = (const float*)d_in[5];   // [128,8]
  float* out = (float*)d_out;                  // [1,128,256,256] f32
  float* ws = (float*)d_ws;

  float* bias_ws = ws;                          // 524288 floats
  float* qkv_ws  = ws + 524288;                 // 25165824 floats
  float* attn_ws = ws + 524288 + 25165824;      // 8388608 floats

  // 1) pair bias
  hipLaunchKernelGGL(bias_kernel, dim3(256), dim3(256), 0, stream,
                     pair, Bp, bias_ws);
  // 2) gate (sigmoid, into d_out as scratch) + qkv projections
  hipLaunchKernelGGL(gemm_gateqkv, dim3(512, 16), dim3(256), 0, stream,
                     msa, Wg, Wqkv, out, qkv_ws);
  // 3) attention per (s,h); reads gate from d_out, writes attn_ws
  hipLaunchKernelGGL(attn_kernel, dim3(S_DIM, H_DIM), dim3(256), 0, stream,
                     qkv_ws, bias_ws, out, attn_ws);
  // 4) output projection -> d_out (overwrites gate scratch)
  hipLaunchKernelGGL(gemm_out, dim3(512, 4), dim3(256), 0, stream,
                     attn_ws, Wout, out);
}

// Round 2
// 136.616 us; speedup vs baseline: 4.7907x; 4.7907x over previous
//
#include <hip/hip_runtime.h>
#include <hip/hip_bf16.h>
#include <math.h>

#define S_DIM 128
#define R_DIM 256
#define M_DIM 256
#define H_DIM 8
#define Z_DIM 128
#define SCALE_F 0.17677669529663687f

typedef __attribute__((ext_vector_type(8))) short bf16x8;
typedef __attribute__((ext_vector_type(4))) short bf16x4;
typedef __attribute__((ext_vector_type(4))) float f32x4;

__device__ inline short bfbits(float f) {
  union { float f; unsigned u; } v; v.f = f;
  unsigned r = v.u + 0x7fffu + ((v.u >> 16) & 1u);
  return (short)(r >> 16);
}

// ---------------------------------------------------------------------------
// Weights prep: Wt[col][k] = {Wg|Wqkv}[k][col] bf16 ; Woutt[col][k] = Wout[k][col]
// ---------------------------------------------------------------------------
__global__ __launch_bounds__(256) void wconv_kernel(
    const float* __restrict__ Wg, const float* __restrict__ Wqkv,
    const float* __restrict__ Wout, short* __restrict__ Wt,
    short* __restrict__ Woutt) {
  int idx = blockIdx.x * 256 + threadIdx.x;
  if (idx < 1024 * 256) {
    int col = idx >> 8, k = idx & 255;
    float v = (col < 256) ? Wg[k * 256 + col] : Wqkv[k * 768 + (col - 256)];
    Wt[idx] = bfbits(v);
  } else {
    int j = idx - 1024 * 256;
    int col = j >> 8, k = j & 255;
    Woutt[j] = bfbits(Wout[k * 256 + col]);
  }
}

// ---------------------------------------------------------------------------
// bias[h][r][p] = sum_z pair[r][p][z] * bproj[z][h]   (f32, unchanged)
// ---------------------------------------------------------------------------
__global__ __launch_bounds__(256) void bias_kernel(
    const float* __restrict__ pair, const float* __restrict__ bproj,
    float* __restrict__ bias) {
  __shared__ float bp[Z_DIM * H_DIM];
  int t = threadIdx.x;
  for (int i = t; i < Z_DIM * H_DIM; i += 256) bp[i] = bproj[i];
  __syncthreads();
  int idx = blockIdx.x * 256 + t;
  const float4* src = (const float4*)(pair + (size_t)idx * Z_DIM);
  float acc[H_DIM] = {};
#pragma unroll
  for (int z4 = 0; z4 < Z_DIM / 4; ++z4) {
    float4 v = src[z4];
    const float* b0 = &bp[z4 * 4 * H_DIM];
#pragma unroll
    for (int h = 0; h < H_DIM; ++h) {
      acc[h] += v.x * b0[h] + v.y * b0[H_DIM + h] +
                v.z * b0[2 * H_DIM + h] + v.w * b0[3 * H_DIM + h];
    }
  }
#pragma unroll
  for (int h = 0; h < H_DIM; ++h)
    bias[(size_t)h * (R_DIM * R_DIM) + idx] = acc[h];
}

// ---------------------------------------------------------------------------
// MFMA GEMM: X[32768,256] f32 @ Wt^T (Wt is [1024][256] bf16, col-major weights)
// cols 0..255 -> sigmoid -> gate (f32), cols 256..1023 -> qkv (bf16)
// tile 128x128, BK=32, 4 waves
// ---------------------------------------------------------------------------
#define GLD 40

__global__ __launch_bounds__(256) void gemm_gateqkv_mfma(
    const float* __restrict__ X, const short* __restrict__ Wt,
    float* __restrict__ gate_out, short* __restrict__ qkv_out) {
  __shared__ short As[128 * GLD];
  __shared__ short Bs[128 * GLD];
  int t = threadIdx.x;
  int lane = t & 63, wid = t >> 6;
  int lq = lane & 15, lg = lane >> 4;
  int wm = wid >> 1, wn = wid & 1;
  int r0 = blockIdx.x * 128, n0 = blockIdx.y * 128;
  f32x4 acc[4][4];
#pragma unroll
  for (int i = 0; i < 4; ++i)
#pragma unroll
    for (int j = 0; j < 4; ++j) acc[i][j] = {0.f, 0.f, 0.f, 0.f};

  for (int k0 = 0; k0 < 256; k0 += 32) {
    __syncthreads();
#pragma unroll
    for (int i = 0; i < 4; ++i) {  // stage A (f32 -> bf16)
      int e = i * 1024 + t * 4;
      int row = e >> 5, kk = e & 31;
      float4 v = *(const float4*)&X[(size_t)(r0 + row) * 256 + k0 + kk];
      bf16x4 b = {bfbits(v.x), bfbits(v.y), bfbits(v.z), bfbits(v.w)};
      *(bf16x4*)&As[row * GLD + kk] = b;
    }
#pragma unroll
    for (int i = 0; i < 2; ++i) {  // stage B (bf16 copy)
      int e8 = (i * 256 + t) * 8;
      int row = e8 >> 5, kk = e8 & 31;
      bf16x8 v = *(const bf16x8*)&Wt[(size_t)(n0 + row) * 256 + k0 + kk];
      *(bf16x8*)&Bs[row * GLD + kk] = v;
    }
    __syncthreads();
    bf16x8 af[4], bfr[4];
#pragma unroll
    for (int mt = 0; mt < 4; ++mt)
      af[mt] = *(const bf16x8*)&As[(wm * 64 + mt * 16 + lq) * GLD + lg * 8];
#pragma unroll
    for (int nt = 0; nt < 4; ++nt)
      bfr[nt] = *(const bf16x8*)&Bs[(wn * 64 + nt * 16 + lq) * GLD + lg * 8];
#pragma unroll
    for (int mt = 0; mt < 4; ++mt)
#pragma unroll
      for (int nt = 0; nt < 4; ++nt)
        acc[mt][nt] = __builtin_amdgcn_mfma_f32_16x16x32_bf16(
            af[mt], bfr[nt], acc[mt][nt], 0, 0, 0);
  }
#pragma unroll
  for (int mt = 0; mt < 4; ++mt) {
#pragma unroll
    for (int nt = 0; nt < 4; ++nt) {
      int col = n0 + wn * 64 + nt * 16 + lq;
#pragma unroll
      for (int j = 0; j < 4; ++j) {
        int row = r0 + wm * 64 + mt * 16 + lg * 4 + j;
        float v = acc[mt][nt][j];
        if (col < 256) {
          gate_out[(size_t)row * 256 + col] = 1.0f / (1.0f + __expf(-v));
        } else {
          qkv_out[(size_t)row * 768 + (col - 256)] = bfbits(v);
        }
      }
    }
  }
}

// ---------------------------------------------------------------------------
// MFMA GEMM: attn[32768,256] f32 @ Woutt^T -> out f32
// ---------------------------------------------------------------------------
__global__ __launch_bounds__(256) void gemm_out_mfma(
    const float* __restrict__ A, const short* __restrict__ Wt,
    float* __restrict__ out) {
  __shared__ short As[128 * GLD];
  __shared__ short Bs[128 * GLD];
  int t = threadIdx.x;
  int lane = t & 63, wid = t >> 6;
  int lq = lane & 15, lg = lane >> 4;
  int wm = wid >> 1, wn = wid & 1;
  int r0 = blockIdx.x * 128, n0 = blockIdx.y * 128;
  f32x4 acc[4][4];
#pragma unroll
  for (int i = 0; i < 4; ++i)
#pragma unroll
    for (int j = 0; j < 4; ++j) acc[i][j] = {0.f, 0.f, 0.f, 0.f};

  for (int k0 = 0; k0 < 256; k0 += 32) {
    __syncthreads();
#pragma unroll
    for (int i = 0; i < 4; ++i) {
      int e = i * 1024 + t * 4;
      int row = e >> 5, kk = e & 31;
      float4 v = *(const float4*)&A[(size_t)(r0 + row) * 256 + k0 + kk];
      bf16x4 b = {bfbits(v.x), bfbits(v.y), bfbits(v.z), bfbits(v.w)};
      *(bf16x4*)&As[row * GLD + kk] = b;
    }
#pragma unroll
    for (int i = 0; i < 2; ++i) {
      int e8 = (i * 256 + t) * 8;
      int row = e8 >> 5, kk = e8 & 31;
      bf16x8 v = *(const bf16x8*)&Wt[(size_t)(n0 + row) * 256 + k0 + kk];
      *(bf16x8*)&Bs[row * GLD + kk] = v;
    }
    __syncthreads();
    bf16x8 af[4], bfr[4];
#pragma unroll
    for (int mt = 0; mt < 4; ++mt)
      af[mt] = *(const bf16x8*)&As[(wm * 64 + mt * 16 + lq) * GLD + lg * 8];
#pragma unroll
    for (int nt = 0; nt < 4; ++nt)
      bfr[nt] = *(const bf16x8*)&Bs[(wn * 64 + nt * 16 + lq) * GLD + lg * 8];
#pragma unroll
    for (int mt = 0; mt < 4; ++mt)
#pragma unroll
      for (int nt = 0; nt < 4; ++nt)
        acc[mt][nt] = __builtin_amdgcn_mfma_f32_16x16x32_bf16(
            af[mt], bfr[nt], acc[mt][nt], 0, 0, 0);
  }
#pragma unroll
  for (int mt = 0; mt < 4; ++mt) {
#pragma unroll
    for (int nt = 0; nt < 4; ++nt) {
      int col = n0 + wn * 64 + nt * 16 + lq;
#pragma unroll
      for (int j = 0; j < 4; ++j) {
        int row = r0 + wm * 64 + mt * 16 + lg * 4 + j;
        out[(size_t)row * 256 + col] = acc[mt][nt][j];
      }
    }
  }
}

// ---------------------------------------------------------------------------
// MFMA attention per (s,h). 8 waves; wave owns 32 r-rows.
// simT = K@Q^T  (D-layout == A-frag layout of P for 16x16x16 MFMA)
// P = exp(sim*scale)/lsum + bias ; attend = P@V ; *gate
// ---------------------------------------------------------------------------
#define VT_LD 260

__global__ __launch_bounds__(512, 2) void attn_mfma(
    const short* __restrict__ qkv, const float* __restrict__ bias,
    const float* __restrict__ gate, float* __restrict__ attn_out) {
  int s = blockIdx.x, h = blockIdx.y;
  __shared__ short Vt[32][VT_LD];
  int t = threadIdx.x;
  int lane = t & 63, wid = t >> 6;
  int lq = lane & 15, lg = lane >> 4;

  // stage V^T : Vt[c][p]
  {
    int p = t & 255, ch = t >> 8;  // ch 0/1 -> c halves
    const short* src = qkv + ((size_t)(s * 256 + p)) * 768 + h * 96 + 64 + ch * 16;
    bf16x8 v0 = *(const bf16x8*)src;
    bf16x8 v1 = *(const bf16x8*)(src + 8);
#pragma unroll
    for (int i = 0; i < 8; ++i) {
      Vt[ch * 16 + i][p] = v0[i];
      Vt[ch * 16 + 8 + i][p] = v1[i];
    }
  }
  __syncthreads();

  int rbase = wid * 32;
  bf16x8 qf[2];
#pragma unroll
  for (int ri = 0; ri < 2; ++ri)
    qf[ri] = *(const bf16x8*)(qkv +
        ((size_t)(s * 256 + rbase + ri * 16 + lq)) * 768 + h * 96 + lg * 8);

  f32x4 acc[2][16];
#pragma unroll
  for (int ri = 0; ri < 2; ++ri)
#pragma unroll
    for (int pt = 0; pt < 16; ++pt) acc[ri][pt] = {0.f, 0.f, 0.f, 0.f};

  // QK^T in two halves of p-tiles (register pressure)
#pragma unroll
  for (int half = 0; half < 2; ++half) {
    bf16x8 kf[8];
#pragma unroll
    for (int i = 0; i < 8; ++i) {
      int pt = half * 8 + i;
      kf[i] = *(const bf16x8*)(qkv +
          ((size_t)(s * 256 + pt * 16 + lq)) * 768 + h * 96 + 32 + lg * 8);
    }
#pragma unroll
    for (int i = 0; i < 8; ++i) {
      int pt = half * 8 + i;
#pragma unroll
      for (int ri = 0; ri < 2; ++ri)
        acc[ri][pt] = __builtin_amdgcn_mfma_f32_16x16x32_bf16(
            kf[i], qf[ri], acc[ri][pt], 0, 0, 0);
    }
  }

  // softmax (no max-subtraction: |sim*scale| < ~1)
  float inv[2];
#pragma unroll
  for (int ri = 0; ri < 2; ++ri) {
    float lsum = 0.f;
#pragma unroll
    for (int pt = 0; pt < 16; ++pt) {
#pragma unroll
      for (int j = 0; j < 4; ++j) {
        float e = __expf(acc[ri][pt][j] * SCALE_F);
        acc[ri][pt][j] = e;
        lsum += e;
      }
    }
    lsum += __shfl_xor(lsum, 16, 64);
    lsum += __shfl_xor(lsum, 32, 64);
    inv[ri] = 1.0f / lsum;
  }

  // P = e/lsum + bias  -> bf16 A-frags (in-register: D layout == A16 layout)
  bf16x4 af[2][16];
#pragma unroll
  for (int ri = 0; ri < 2; ++ri) {
    int r = rbase + ri * 16 + lq;
    const float4* bp =
        (const float4*)(bias + ((size_t)h << 16) + (size_t)r * 256 + lg * 4);
#pragma unroll
    for (int pt = 0; pt < 16; ++pt) {
      float4 b = bp[pt * 4];
      af[ri][pt] = {bfbits(acc[ri][pt][0] * inv[ri] + b.x),
                    bfbits(acc[ri][pt][1] * inv[ri] + b.y),
                    bfbits(acc[ri][pt][2] * inv[ri] + b.z),
                    bfbits(acc[ri][pt][3] * inv[ri] + b.w)};
    }
  }

  // PV: attend[r][c] += P[r][p] * V[p][c]  (16x16x16 MFMA, K=16 chunks)
  f32x4 oacc[2][2];
#pragma unroll
  for (int ri = 0; ri < 2; ++ri)
#pragma unroll
    for (int ct = 0; ct < 2; ++ct) oacc[ri][ct] = {0.f, 0.f, 0.f, 0.f};

#pragma unroll
  for (int kc = 0; kc < 16; ++kc) {
    bf16x4 vf0 = *(const bf16x4*)&Vt[lq][kc * 16 + lg * 4];
    bf16x4 vf1 = *(const bf16x4*)&Vt[16 + lq][kc * 16 + lg * 4];
#pragma unroll
    for (int ri = 0; ri < 2; ++ri) {
      oacc[ri][0] = __builtin_amdgcn_mfma_f32_16x16x16bf16_1k(
          af[ri][kc], vf0, oacc[ri][0], 0, 0, 0);
      oacc[ri][1] = __builtin_amdgcn_mfma_f32_16x16x16bf16_1k(
          af[ri][kc], vf1, oacc[ri][1], 0, 0, 0);
    }
  }

  // epilogue: * gate, store f32
#pragma unroll
  for (int ri = 0; ri < 2; ++ri) {
#pragma unroll
    for (int ct = 0; ct < 2; ++ct) {
      int colg = h * 32 + ct * 16 + lq;
#pragma unroll
      for (int j = 0; j < 4; ++j) {
        int rowg = s * 256 + rbase + ri * 16 + lg * 4 + j;
        size_t o = (size_t)rowg * 256 + colg;
        attn_out[o] = oacc[ri][ct][j] * gate[o];
      }
    }
  }
}

// ---------------------------------------------------------------------------
extern "C" void kernel_launch(void* const* d_in, const int* in_sizes, int n_in,
                              void* d_out, int out_size, void* d_ws,
                              size_t ws_size, hipStream_t stream) {
  const float* msa  = (const float*)d_in[0];
  const float* pair = (const float*)d_in[1];
  const float* Wg   = (const float*)d_in[2];
  const float* Wqkv = (const float*)d_in[3];
  const float* Wout = (const float*)d_in[4];
  const float* Bp   = (const float*)d_in[5];
  float* out = (float*)d_out;
  float* ws = (float*)d_ws;

  float* bias_ws = ws;                         // 524288 f32
  float* gate_ws = ws + 524288;                // 8388608 f32
  float* attn_ws = ws + 8912896;               // 8388608 f32
  short* qkv_bf  = (short*)(ws + 17301504);    // 25165824 bf16
  short* Wt_bf   = (short*)(ws + 29884416);    // 262144 bf16
  short* Woutt_bf= (short*)(ws + 30015488);    // 65536 bf16

  hipLaunchKernelGGL(wconv_kernel, dim3(1280), dim3(256), 0, stream,
                     Wg, Wqkv, Wout, Wt_bf, Woutt_bf);
  hipLaunchKernelGGL(bias_kernel, dim3(256), dim3(256), 0, stream,
                     pair, Bp, bias_ws);
  hipLaunchKernelGGL(gemm_gateqkv_mfma, dim3(256, 8), dim3(256), 0, stream,
                     msa, Wt_bf, gate_ws, qkv_bf);
  hipLaunchKernelGGL(attn_mfma, dim3(S_DIM, H_DIM), dim3(512), 0, stream,
                     qkv_bf, bias_ws, gate_ws, attn_ws);
  hipLaunchKernelGGL(gemm_out_mfma, dim3(256, 2), dim3(256), 0, stream,
                     attn_ws, Woutt_bf, out);
}

// Round 4
// 123.573 us; speedup vs baseline: 5.2964x; 1.1056x over previous
//
#include <hip/hip_runtime.h>
#include <hip/hip_bf16.h>
#include <math.h>

typedef __attribute__((ext_vector_type(8))) short bf16x8;
typedef __attribute__((ext_vector_type(4))) short bf16x4;
typedef __attribute__((ext_vector_type(4))) float f32x4;

#define MFMA32 __builtin_amdgcn_mfma_f32_16x16x32_bf16
#define MFMA16 __builtin_amdgcn_mfma_f32_16x16x16bf16_1k

#define QSCALE 0.25503485964546277f  // (1/sqrt(32)) * log2(e)

__device__ inline short bfbits(float f) {
  union { float f; unsigned u; } v; v.f = f;
  unsigned r = v.u + 0x7fffu + ((v.u >> 16) & 1u);
  return (short)(r >> 16);
}
__device__ inline float bf2f(unsigned short u) {
  union { unsigned u; float f; } v; v.u = ((unsigned)u) << 16; return v.f;
}
__device__ inline void gll16(const void* g, void* l) {
  __builtin_amdgcn_global_load_lds(
      (const __attribute__((address_space(1))) unsigned*)g,
      (__attribute__((address_space(3))) unsigned*)l, 16, 0, 0);
}

// ---------------------------------------------------------------------------
// wconv: Wt[col][k] bf16 (cols 0..255 gate, 256..1023 qkv w/ q-cols pre-scaled
// by QSCALE); Woutt[col][k] bf16.
// ---------------------------------------------------------------------------
__global__ __launch_bounds__(256) void wconv_kernel(
    const float* __restrict__ Wg, const float* __restrict__ Wqkv,
    const float* __restrict__ Wout, short* __restrict__ Wt,
    short* __restrict__ Woutt) {
  int idx = blockIdx.x * 256 + threadIdx.x;
  if (idx < 1024 * 256) {
    int col = idx >> 8, k = idx & 255;
    float v;
    if (col < 256) {
      v = Wg[k * 256 + col];
    } else {
      int wc = col - 256;
      v = Wqkv[k * 768 + wc];
      if ((wc % 96) < 32) v *= QSCALE;
    }
    Wt[idx] = bfbits(v);
  } else {
    int j = idx - 1024 * 256;
    int col = j >> 8, k = j & 255;
    Woutt[j] = bfbits(Wout[k * 256 + col]);
  }
}

// ---------------------------------------------------------------------------
// bias_bf[h][r][p] = bf16( sum_z pair[r][p][z] * bproj[z][h] )
// ---------------------------------------------------------------------------
__global__ __launch_bounds__(256) void bias_kernel(
    const float* __restrict__ pair, const float* __restrict__ bproj,
    short* __restrict__ bias_bf) {
  __shared__ float bp[128 * 8];
  int t = threadIdx.x;
  for (int i = t; i < 128 * 8; i += 256) bp[i] = bproj[i];
  __syncthreads();
  int idx = blockIdx.x * 256 + t;
  const float4* src = (const float4*)(pair + (size_t)idx * 128);
  float acc[8] = {};
#pragma unroll
  for (int z4 = 0; z4 < 32; ++z4) {
    float4 v = src[z4];
    const float* b0 = &bp[z4 * 32];
#pragma unroll
    for (int h = 0; h < 8; ++h) {
      acc[h] += v.x * b0[h] + v.y * b0[8 + h] +
                v.z * b0[16 + h] + v.w * b0[24 + h];
    }
  }
#pragma unroll
  for (int h = 0; h < 8; ++h)
    bias_bf[(size_t)h * 65536 + idx] = bfbits(acc[h]);
}

// ---------------------------------------------------------------------------
// gemm_fused: X[32768,256]f32 @ Wt^T[256,1024] -> gate(sigmoid,bf16) | qkv(bf16)
// 256 blocks, 512 thr (8 waves 2m x 4n). A panel staged once (swizzled);
// B double-buffered via global_load_lds (pre-swizzled source).
// ---------------------------------------------------------------------------
__global__ __launch_bounds__(512) void gemm_fused(
    const float* __restrict__ X, const short* __restrict__ Wt,
    short* __restrict__ gate_bf, short* __restrict__ qkv_bf) {
  __shared__ short As[128 * 256];      // 64KB
  __shared__ short Bs[2][256 * 64];    // 2 x 32KB
  int t = threadIdx.x;
  int lane = t & 63, wid = t >> 6;
  int lq = lane & 15, lg = lane >> 4;
  int wm = wid >> 2, wn = wid & 3;
  int r0 = blockIdx.x * 128;

  // stage A once: f32 -> bf16, XOR-swizzled ds_write
  {
    int row = t >> 2;
    int kb = (t & 3) * 64;
    const float* xrow = &X[(size_t)(r0 + row) * 256 + kb];
    int swz = (row & 7) << 4;
#pragma unroll
    for (int q = 0; q < 8; ++q) {
      float4 va = *(const float4*)(xrow + q * 8);
      float4 vb = *(const float4*)(xrow + q * 8 + 4);
      bf16x8 o = {bfbits(va.x), bfbits(va.y), bfbits(va.z), bfbits(va.w),
                  bfbits(vb.x), bfbits(vb.y), bfbits(vb.z), bfbits(vb.w)};
      int kbyte = kb * 2 + q * 16;
      *(bf16x8*)((char*)As + row * 512 + (kbyte ^ swz)) = o;
    }
  }

  auto stage = [&](int step, int buf) {
    int nt2 = step >> 2, k642 = step & 3;
#pragma unroll
    for (int q = 0; q < 4; ++q) {
      int P = wid * 4096 + q * 1024 + lane * 16;
      int col = P >> 7, kb = P & 127;
      int klog = kb ^ ((col & 7) << 4);
      gll16((const char*)Wt + ((size_t)(nt2 * 256 + col) * 512 + k642 * 128 + klog),
            (char*)&Bs[buf][0] + wid * 4096 + q * 1024);
    }
  };

  f32x4 acc[4][4];
#pragma unroll
  for (int a = 0; a < 4; ++a)
#pragma unroll
    for (int b = 0; b < 4; ++b) acc[a][b] = {0.f, 0.f, 0.f, 0.f};

  stage(0, 0);
  __syncthreads();

  for (int s = 0; s < 16; ++s) {
    int ntile = s >> 2, k64 = s & 3;
    if (s < 15) stage(s + 1, (s + 1) & 1);
    const char* bbase = (const char*)&Bs[s & 1][0];
    bf16x8 afr[4][2], bfr[4][2];
#pragma unroll
    for (int kcl = 0; kcl < 2; ++kcl) {
#pragma unroll
      for (int mf = 0; mf < 4; ++mf) {
        int row = wm * 64 + mf * 16 + lq;
        int kbyte = k64 * 128 + ((((kcl << 6) | (lg << 4))) ^ ((row & 7) << 4));
        afr[mf][kcl] = *(const bf16x8*)((const char*)As + row * 512 + kbyte);
      }
#pragma unroll
      for (int nf = 0; nf < 4; ++nf) {
        int col = wn * 64 + nf * 16 + lq;
        int kbyte = (((kcl << 6) | (lg << 4))) ^ ((col & 7) << 4);
        bfr[nf][kcl] = *(const bf16x8*)(bbase + col * 128 + kbyte);
      }
    }
#pragma unroll
    for (int mf = 0; mf < 4; ++mf)
#pragma unroll
      for (int nf = 0; nf < 4; ++nf)
#pragma unroll
        for (int kcl = 0; kcl < 2; ++kcl)
          acc[mf][nf] = MFMA32(afr[mf][kcl], bfr[nf][kcl], acc[mf][nf], 0, 0, 0);
    __syncthreads();

    if (k64 == 3) {
      if (ntile == 0) {
#pragma unroll
        for (int mf = 0; mf < 4; ++mf)
#pragma unroll
          for (int nf = 0; nf < 4; ++nf) {
            int col = wn * 64 + nf * 16 + lq;
#pragma unroll
            for (int j = 0; j < 4; ++j) {
              int row = r0 + wm * 64 + mf * 16 + lg * 4 + j;
              float v = acc[mf][nf][j];
              float sg = __builtin_amdgcn_rcpf(1.f + __expf(-v));
              gate_bf[(size_t)row * 256 + col] = bfbits(sg);
            }
          }
      } else {
        int cb = ntile * 256 - 256;
#pragma unroll
        for (int mf = 0; mf < 4; ++mf)
#pragma unroll
          for (int nf = 0; nf < 4; ++nf) {
            int col = cb + wn * 64 + nf * 16 + lq;
#pragma unroll
            for (int j = 0; j < 4; ++j) {
              int row = r0 + wm * 64 + mf * 16 + lg * 4 + j;
              qkv_bf[(size_t)row * 768 + col] = bfbits(acc[mf][nf][j]);
            }
          }
      }
#pragma unroll
      for (int a = 0; a < 4; ++a)
#pragma unroll
        for (int b = 0; b < 4; ++b) acc[a][b] = {0.f, 0.f, 0.f, 0.f};
    }
  }
}

// ---------------------------------------------------------------------------
// attn: grid (128 s, 8 h, 2 z), 256 thr (4 waves x 32 rows).
// simT = K@Q^T (q pre-scaled by QSCALE); E = exp2(simT);
// attend = (E@V) * rcp(E@1) + bias@V; * gate; -> bf16
// ---------------------------------------------------------------------------
__global__ __launch_bounds__(256) void attn_mfma2(
    const short* __restrict__ qkv, const short* __restrict__ bias_bf,
    const short* __restrict__ gate_bf, short* __restrict__ attn_bf) {
  int s = blockIdx.x, h = blockIdx.y, z = blockIdx.z;
  __shared__ short Vt[32][260];
  int t = threadIdx.x;
  int lane = t & 63, wid = t >> 6;
  int lq = lane & 15, lg = lane >> 4;

  {  // stage V^T: Vt[c][p]
    int p = t;
    const short* src = qkv + ((size_t)(s * 256 + p)) * 768 + h * 96 + 64;
    bf16x8 v0 = *(const bf16x8*)src;
    bf16x8 v1 = *(const bf16x8*)(src + 8);
    bf16x8 v2 = *(const bf16x8*)(src + 16);
    bf16x8 v3 = *(const bf16x8*)(src + 24);
#pragma unroll
    for (int i = 0; i < 8; ++i) {
      Vt[i][p] = v0[i];      Vt[8 + i][p] = v1[i];
      Vt[16 + i][p] = v2[i]; Vt[24 + i][p] = v3[i];
    }
  }
  __syncthreads();

  int rbase = z * 128 + wid * 32;
  const short* qbase = qkv + (size_t)s * 256 * 768 + h * 96;
  bf16x8 qf0 = *(const bf16x8*)(qbase + (size_t)(rbase + lq) * 768 + lg * 8);
  bf16x8 qf1 = *(const bf16x8*)(qbase + (size_t)(rbase + 16 + lq) * 768 + lg * 8);
  const short* kbase = qbase + 32 + (size_t)lq * 768 + lg * 8;
  const short* bb0 = bias_bf + ((size_t)h * 256 + rbase + lq) * 256 + lg * 4;
  const short* bb1 = bb0 + 16 * 256;

  f32x4 U[2][2], BV[2][2], L[2];
#pragma unroll
  for (int ri = 0; ri < 2; ++ri) {
    L[ri] = {0.f, 0.f, 0.f, 0.f};
#pragma unroll
    for (int ct = 0; ct < 2; ++ct) {
      U[ri][ct] = {0.f, 0.f, 0.f, 0.f};
      BV[ri][ct] = {0.f, 0.f, 0.f, 0.f};
    }
  }
  const bf16x4 ones = {16256, 16256, 16256, 16256};  // bf16 1.0 x4

#pragma unroll
  for (int qtr = 0; qtr < 4; ++qtr) {
    bf16x8 kf[4];
    bf16x4 bfr[2][4];
#pragma unroll
    for (int i = 0; i < 4; ++i) {
      int pt = qtr * 4 + i;
      kf[i] = *(const bf16x8*)(kbase + (size_t)pt * 16 * 768);
      bfr[0][i] = *(const bf16x4*)(bb0 + pt * 16);
      bfr[1][i] = *(const bf16x4*)(bb1 + pt * 16);
    }
    f32x4 acc[2][4];
#pragma unroll
    for (int ri = 0; ri < 2; ++ri)
#pragma unroll
      for (int i = 0; i < 4; ++i) acc[ri][i] = {0.f, 0.f, 0.f, 0.f};
#pragma unroll
    for (int i = 0; i < 4; ++i) {
      acc[0][i] = MFMA32(kf[i], qf0, acc[0][i], 0, 0, 0);
      acc[1][i] = MFMA32(kf[i], qf1, acc[1][i], 0, 0, 0);
    }
    bf16x4 af[2][4];
#pragma unroll
    for (int ri = 0; ri < 2; ++ri)
#pragma unroll
      for (int i = 0; i < 4; ++i)
#pragma unroll
        for (int j = 0; j < 4; ++j)
          af[ri][i][j] = bfbits(exp2f(acc[ri][i][j]));
#pragma unroll
    for (int i = 0; i < 4; ++i) {
      int kc = qtr * 4 + i;
      bf16x4 vf0 = *(const bf16x4*)&Vt[lq][kc * 16 + lg * 4];
      bf16x4 vf1 = *(const bf16x4*)&Vt[16 + lq][kc * 16 + lg * 4];
#pragma unroll
      for (int ri = 0; ri < 2; ++ri) {
        U[ri][0] = MFMA16(af[ri][i], vf0, U[ri][0], 0, 0, 0);
        U[ri][1] = MFMA16(af[ri][i], vf1, U[ri][1], 0, 0, 0);
        L[ri]    = MFMA16(af[ri][i], ones, L[ri], 0, 0, 0);
        BV[ri][0] = MFMA16(bfr[ri][i], vf0, BV[ri][0], 0, 0, 0);
        BV[ri][1] = MFMA16(bfr[ri][i], vf1, BV[ri][1], 0, 0, 0);
      }
    }
  }

#pragma unroll
  for (int ri = 0; ri < 2; ++ri) {
    f32x4 inv;
#pragma unroll
    for (int j = 0; j < 4; ++j) inv[j] = __builtin_amdgcn_rcpf(L[ri][j]);
#pragma unroll
    for (int ct = 0; ct < 2; ++ct) {
      int colg = h * 32 + ct * 16 + lq;
#pragma unroll
      for (int j = 0; j < 4; ++j) {
        int rowg = s * 256 + rbase + ri * 16 + lg * 4 + j;
        size_t o = (size_t)rowg * 256 + colg;
        float g = bf2f(((const unsigned short*)gate_bf)[o]);
        attn_bf[o] = bfbits((U[ri][ct][j] * inv[j] + BV[ri][ct][j]) * g);
      }
    }
  }
}

// ---------------------------------------------------------------------------
// gemm_out: attn_bf[32768,256] @ Woutt^T -> out f32. Both operands via
// double-buffered global_load_lds (pre-swizzled source).
// ---------------------------------------------------------------------------
__global__ __launch_bounds__(256) void gemm_out2(
    const short* __restrict__ A, const short* __restrict__ Wt,
    float* __restrict__ out) {
  __shared__ short As2[2][128 * 64];
  __shared__ short Bs2[2][128 * 64];
  int t = threadIdx.x;
  int lane = t & 63, wid = t >> 6;
  int lq = lane & 15, lg = lane >> 4;
  int wm = wid >> 1, wn = wid & 1;
  int r0 = blockIdx.x * 128, n0 = blockIdx.y * 128;

  auto stage = [&](int s, int buf) {
#pragma unroll
    for (int q = 0; q < 4; ++q) {
      int P = wid * 4096 + q * 1024 + lane * 16;
      int row = P >> 7, kb = P & 127;
      int klog = kb ^ ((row & 7) << 4);
      gll16((const char*)A + ((size_t)(r0 + row) * 512 + s * 128 + klog),
            (char*)&As2[buf][0] + wid * 4096 + q * 1024);
      gll16((const char*)Wt + ((size_t)(n0 + row) * 512 + s * 128 + klog),
            (char*)&Bs2[buf][0] + wid * 4096 + q * 1024);
    }
  };

  f32x4 acc[4][4];
#pragma unroll
  for (int a = 0; a < 4; ++a)
#pragma unroll
    for (int b = 0; b < 4; ++b) acc[a][b] = {0.f, 0.f, 0.f, 0.f};

  stage(0, 0);
  __syncthreads();
  for (int s = 0; s < 4; ++s) {
    if (s < 3) stage(s + 1, (s + 1) & 1);
    bf16x8 afr[4][2], bfr[4][2];
#pragma unroll
    for (int kcl = 0; kcl < 2; ++kcl) {
#pragma unroll
      for (int mf = 0; mf < 4; ++mf) {
        int row = wm * 64 + mf * 16 + lq;
        int kb = (((kcl << 6) | (lg << 4))) ^ ((row & 7) << 4);
        afr[mf][kcl] = *(const bf16x8*)((const char*)&As2[s & 1][0] + row * 128 + kb);
      }
#pragma unroll
      for (int nf = 0; nf < 4; ++nf) {
        int col = wn * 64 + nf * 16 + lq;
        int kb = (((kcl << 6) | (lg << 4))) ^ ((col & 7) << 4);
        bfr[nf][kcl] = *(const bf16x8*)((const char*)&Bs2[s & 1][0] + col * 128 + kb);
      }
    }
#pragma unroll
    for (int mf = 0; mf < 4; ++mf)
#pragma unroll
      for (int nf = 0; nf < 4; ++nf)
#pragma unroll
        for (int kcl = 0; kcl < 2; ++kcl)
          acc[mf][nf] = MFMA32(afr[mf][kcl], bfr[nf][kcl], acc[mf][nf], 0, 0, 0);
    __syncthreads();
  }
#pragma unroll
  for (int mf = 0; mf < 4; ++mf)
#pragma unroll
    for (int nf = 0; nf < 4; ++nf) {
      int col = n0 + wn * 64 + nf * 16 + lq;
#pragma unroll
      for (int j = 0; j < 4; ++j) {
        int row = r0 + wm * 64 + mf * 16 + lg * 4 + j;
        out[(size_t)row * 256 + col] = acc[mf][nf][j];
      }
    }
}

// ---------------------------------------------------------------------------
extern "C" void kernel_launch(void* const* d_in, const int* in_sizes, int n_in,
                              void* d_out, int out_size, void* d_ws,
                              size_t ws_size, hipStream_t stream) {
  const float* msa  = (const float*)d_in[0];
  const float* pair = (const float*)d_in[1];
  const float* Wg   = (const float*)d_in[2];
  const float* Wqkv = (const float*)d_in[3];
  const float* Wout = (const float*)d_in[4];
  const float* Bp   = (const float*)d_in[5];
  float* out = (float*)d_out;
  short* sw = (short*)d_ws;

  short* bias_bf = sw;                 //   524288 shorts
  short* gate_bf = sw + 524288;        //  8388608
  short* qkv_bf  = sw + 8912896;       // 25165824
  short* attn_bf = sw + 34078720;      //  8388608
  short* Wt_bf   = sw + 42467328;      //   262144
  short* Woutt   = sw + 42729472;      //    65536

  hipLaunchKernelGGL(wconv_kernel, dim3(1280), dim3(256), 0, stream,
                     Wg, Wqkv, Wout, Wt_bf, Woutt);
  hipLaunchKernelGGL(bias_kernel, dim3(256), dim3(256), 0, stream,
                     pair, Bp, bias_bf);
  hipLaunchKernelGGL(gemm_fused, dim3(256), dim3(512), 0, stream,
                     msa, Wt_bf, gate_bf, qkv_bf);
  hipLaunchKernelGGL(attn_mfma2, dim3(128, 8, 2), dim3(256), 0, stream,
                     qkv_bf, bias_bf, gate_bf, attn_bf);
  hipLaunchKernelGGL(gemm_out2, dim3(256, 2), dim3(256), 0, stream,
                     attn_bf, Woutt, out);
}

// Round 5
// 106.845 us; speedup vs baseline: 6.1256x; 1.1566x over previous
//
#include <hip/hip_runtime.h>
#include <hip/hip_bf16.h>
#include <math.h>

typedef __attribute__((ext_vector_type(8))) short bf16x8;
typedef __attribute__((ext_vector_type(4))) short bf16x4;
typedef __attribute__((ext_vector_type(4))) float f32x4;

#define MFMA32 __builtin_amdgcn_mfma_f32_16x16x32_bf16
#define MFMA16 __builtin_amdgcn_mfma_f32_16x16x16bf16_1k

#define QSCALE 0.25503485964546277f  // (1/sqrt(32)) * log2(e)

__device__ inline short bfbits(float f) {
  union { float f; unsigned u; } v; v.f = f;
  unsigned r = v.u + 0x7fffu + ((v.u >> 16) & 1u);
  return (short)(r >> 16);
}
__device__ inline float bf2f(unsigned short u) {
  union { unsigned u; float f; } v; v.u = ((unsigned)u) << 16; return v.f;
}
__device__ inline void gll16(const void* g, void* l) {
  __builtin_amdgcn_global_load_lds(
      (const __attribute__((address_space(1))) unsigned*)g,
      (__attribute__((address_space(3))) unsigned*)l, 16, 0, 0);
}

// ---------------------------------------------------------------------------
// wconv: Wt[col][k] bf16 (cols 0..255 gate, 256..1023 qkv w/ q-cols pre-scaled
// by QSCALE); Woutt[col][k] bf16.
// ---------------------------------------------------------------------------
__global__ __launch_bounds__(256) void wconv_kernel(
    const float* __restrict__ Wg, const float* __restrict__ Wqkv,
    const float* __restrict__ Wout, short* __restrict__ Wt,
    short* __restrict__ Woutt) {
  int idx = blockIdx.x * 256 + threadIdx.x;
  if (idx < 1024 * 256) {
    int col = idx >> 8, k = idx & 255;
    float v;
    if (col < 256) {
      v = Wg[k * 256 + col];
    } else {
      int wc = col - 256;
      v = Wqkv[k * 768 + wc];
      if ((wc % 96) < 32) v *= QSCALE;
    }
    Wt[idx] = bfbits(v);
  } else {
    int j = idx - 1024 * 256;
    int col = j >> 8, k = j & 255;
    Woutt[j] = bfbits(Wout[k * 256 + col]);
  }
}

// ---------------------------------------------------------------------------
// bias_bf[h][r][p] = bf16( sum_z pair[r][p][z] * bproj[z][h] )
// ---------------------------------------------------------------------------
__global__ __launch_bounds__(256) void bias_kernel(
    const float* __restrict__ pair, const float* __restrict__ bproj,
    short* __restrict__ bias_bf) {
  __shared__ float bp[128 * 8];
  int t = threadIdx.x;
  for (int i = t; i < 128 * 8; i += 256) bp[i] = bproj[i];
  __syncthreads();
  int idx = blockIdx.x * 256 + t;
  const float4* src = (const float4*)(pair + (size_t)idx * 128);
  float acc[8] = {};
#pragma unroll
  for (int z4 = 0; z4 < 32; ++z4) {
    float4 v = src[z4];
    const float* b0 = &bp[z4 * 32];
#pragma unroll
    for (int h = 0; h < 8; ++h) {
      acc[h] += v.x * b0[h] + v.y * b0[8 + h] +
                v.z * b0[16 + h] + v.w * b0[24 + h];
    }
  }
#pragma unroll
  for (int h = 0; h < 8; ++h)
    bias_bf[(size_t)h * 65536 + idx] = bfbits(acc[h]);
}

// ---------------------------------------------------------------------------
// gemm_fused: X[32768,256]f32 @ Wt^T[256,1024] -> gate(sigmoid,bf16) | qkv(bf16)
// ---------------------------------------------------------------------------
__global__ __launch_bounds__(512) void gemm_fused(
    const float* __restrict__ X, const short* __restrict__ Wt,
    short* __restrict__ gate_bf, short* __restrict__ qkv_bf) {
  __shared__ short As[128 * 256];      // 64KB
  __shared__ short Bs[2][256 * 64];    // 2 x 32KB
  int t = threadIdx.x;
  int lane = t & 63, wid = t >> 6;
  int lq = lane & 15, lg = lane >> 4;
  int wm = wid >> 2, wn = wid & 3;
  int r0 = blockIdx.x * 128;

  {
    int row = t >> 2;
    int kb = (t & 3) * 64;
    const float* xrow = &X[(size_t)(r0 + row) * 256 + kb];
    int swz = (row & 7) << 4;
#pragma unroll
    for (int q = 0; q < 8; ++q) {
      float4 va = *(const float4*)(xrow + q * 8);
      float4 vb = *(const float4*)(xrow + q * 8 + 4);
      bf16x8 o = {bfbits(va.x), bfbits(va.y), bfbits(va.z), bfbits(va.w),
                  bfbits(vb.x), bfbits(vb.y), bfbits(vb.z), bfbits(vb.w)};
      int kbyte = kb * 2 + q * 16;
      *(bf16x8*)((char*)As + row * 512 + (kbyte ^ swz)) = o;
    }
  }

  auto stage = [&](int step, int buf) {
    int nt2 = step >> 2, k642 = step & 3;
#pragma unroll
    for (int q = 0; q < 4; ++q) {
      int P = wid * 4096 + q * 1024 + lane * 16;
      int col = P >> 7, kb = P & 127;
      int klog = kb ^ ((col & 7) << 4);
      gll16((const char*)Wt + ((size_t)(nt2 * 256 + col) * 512 + k642 * 128 + klog),
            (char*)&Bs[buf][0] + wid * 4096 + q * 1024);
    }
  };

  f32x4 acc[4][4];
#pragma unroll
  for (int a = 0; a < 4; ++a)
#pragma unroll
    for (int b = 0; b < 4; ++b) acc[a][b] = {0.f, 0.f, 0.f, 0.f};

  stage(0, 0);
  __syncthreads();

  for (int s = 0; s < 16; ++s) {
    int ntile = s >> 2, k64 = s & 3;
    if (s < 15) stage(s + 1, (s + 1) & 1);
    const char* bbase = (const char*)&Bs[s & 1][0];
    bf16x8 afr[4][2], bfr[4][2];
#pragma unroll
    for (int kcl = 0; kcl < 2; ++kcl) {
#pragma unroll
      for (int mf = 0; mf < 4; ++mf) {
        int row = wm * 64 + mf * 16 + lq;
        int kbyte = k64 * 128 + ((((kcl << 6) | (lg << 4))) ^ ((row & 7) << 4));
        afr[mf][kcl] = *(const bf16x8*)((const char*)As + row * 512 + kbyte);
      }
#pragma unroll
      for (int nf = 0; nf < 4; ++nf) {
        int col = wn * 64 + nf * 16 + lq;
        int kbyte = (((kcl << 6) | (lg << 4))) ^ ((col & 7) << 4);
        bfr[nf][kcl] = *(const bf16x8*)(bbase + col * 128 + kbyte);
      }
    }
#pragma unroll
    for (int mf = 0; mf < 4; ++mf)
#pragma unroll
      for (int nf = 0; nf < 4; ++nf)
#pragma unroll
        for (int kcl = 0; kcl < 2; ++kcl)
          acc[mf][nf] = MFMA32(afr[mf][kcl], bfr[nf][kcl], acc[mf][nf], 0, 0, 0);
    __syncthreads();

    if (k64 == 3) {
      if (ntile == 0) {
#pragma unroll
        for (int mf = 0; mf < 4; ++mf)
#pragma unroll
          for (int nf = 0; nf < 4; ++nf) {
            int col = wn * 64 + nf * 16 + lq;
#pragma unroll
            for (int j = 0; j < 4; ++j) {
              int row = r0 + wm * 64 + mf * 16 + lg * 4 + j;
              float v = acc[mf][nf][j];
              float sg = __builtin_amdgcn_rcpf(1.f + __expf(-v));
              gate_bf[(size_t)row * 256 + col] = bfbits(sg);
            }
          }
      } else {
        int cb = ntile * 256 - 256;
#pragma unroll
        for (int mf = 0; mf < 4; ++mf)
#pragma unroll
          for (int nf = 0; nf < 4; ++nf) {
            int col = cb + wn * 64 + nf * 16 + lq;
#pragma unroll
            for (int j = 0; j < 4; ++j) {
              int row = r0 + wm * 64 + mf * 16 + lg * 4 + j;
              qkv_bf[(size_t)row * 768 + col] = bfbits(acc[mf][nf][j]);
            }
          }
      }
#pragma unroll
      for (int a = 0; a < 4; ++a)
#pragma unroll
        for (int b = 0; b < 4; ++b) acc[a][b] = {0.f, 0.f, 0.f, 0.f};
    }
  }
}

// ---------------------------------------------------------------------------
// attn v3: one block per (s,h), 512 thr (8 waves x 32 rows).
// K staged in LDS via global_load_lds (swizzled slots); V^T staged in LDS.
// simT = K@Q^T; E = exp2(simT); attend = (E@V)*rcp(E@1) + bias@V.
// Epilogue: results -> LDS (reuse K buf) -> coalesced gate-mul + store.
// ---------------------------------------------------------------------------
__global__ __launch_bounds__(512) void attn_mfma3(
    const short* __restrict__ qkv, const short* __restrict__ bias_bf,
    const short* __restrict__ gate_bf, short* __restrict__ attn_bf) {
  int s = blockIdx.x, h = blockIdx.y;
  __shared__ short Ks[8192];       // [256 p][4 slots of 16B], slot-swizzled
  __shared__ short Vt[32][260];    // V^T [c][p]
  short* Res = Ks;                 // reused after PV (barrier-protected)
  int t = threadIdx.x;
  int lane = t & 63, wid = t >> 6;
  int lq = lane & 15, lg = lane >> 4;
  const short* qkv_s = qkv + (size_t)s * 196608 + h * 96;

  // stage K: LDS linear dest, pre-swizzled global source (slot^((p>>1)&3))
#pragma unroll
  for (int q = 0; q < 2; ++q) {
    int off = wid * 2048 + q * 1024 + lane * 16;  // byte offset in Ks
    int p = off >> 6;
    int slot = (off >> 4) & 3;
    int cg = slot ^ ((p >> 1) & 3);
    gll16(qkv_s + p * 768 + 32 + cg * 8, (char*)Ks + wid * 2048 + q * 1024);
  }
  // stage V^T (register transpose)
  {
    int p = t >> 1, hf = t & 1;
    const short* src = qkv_s + p * 768 + 64 + hf * 16;
    bf16x8 v0 = *(const bf16x8*)src;
    bf16x8 v1 = *(const bf16x8*)(src + 8);
#pragma unroll
    for (int i = 0; i < 8; ++i) {
      Vt[hf * 16 + i][p] = v0[i];
      Vt[hf * 16 + 8 + i][p] = v1[i];
    }
  }

  int rbase = wid * 32;
  bf16x8 qf0 = *(const bf16x8*)(qkv_s + (size_t)(rbase + lq) * 768 + lg * 8);
  bf16x8 qf1 = *(const bf16x8*)(qkv_s + (size_t)(rbase + 16 + lq) * 768 + lg * 8);
  const short* bb0 = bias_bf + ((size_t)h * 256 + rbase + lq) * 256 + lg * 4;
  const short* bb1 = bb0 + 16 * 256;

  f32x4 U[2][2], BV[2][2], L[2];
#pragma unroll
  for (int ri = 0; ri < 2; ++ri) {
    L[ri] = {0.f, 0.f, 0.f, 0.f};
#pragma unroll
    for (int ct = 0; ct < 2; ++ct) {
      U[ri][ct] = {0.f, 0.f, 0.f, 0.f};
      BV[ri][ct] = {0.f, 0.f, 0.f, 0.f};
    }
  }
  const bf16x4 ones = {16256, 16256, 16256, 16256};  // bf16 1.0

  __syncthreads();

#pragma unroll
  for (int qtr = 0; qtr < 4; ++qtr) {
    bf16x8 kf[4];
    bf16x4 bfr[2][4];
#pragma unroll
    for (int i = 0; i < 4; ++i) {
      int pt = qtr * 4 + i;
      int row = pt * 16 + lq;
      kf[i] = *(const bf16x8*)((const char*)Ks + row * 64 +
                               ((lg ^ ((row >> 1) & 3)) << 4));
      bfr[0][i] = *(const bf16x4*)(bb0 + pt * 16);
      bfr[1][i] = *(const bf16x4*)(bb1 + pt * 16);
    }
    f32x4 acc[2][4];
#pragma unroll
    for (int ri = 0; ri < 2; ++ri)
#pragma unroll
      for (int i = 0; i < 4; ++i) acc[ri][i] = {0.f, 0.f, 0.f, 0.f};
#pragma unroll
    for (int i = 0; i < 4; ++i) {
      acc[0][i] = MFMA32(kf[i], qf0, acc[0][i], 0, 0, 0);
      acc[1][i] = MFMA32(kf[i], qf1, acc[1][i], 0, 0, 0);
    }
    bf16x4 af[2][4];
#pragma unroll
    for (int ri = 0; ri < 2; ++ri)
#pragma unroll
      for (int i = 0; i < 4; ++i)
#pragma unroll
        for (int j = 0; j < 4; ++j)
          af[ri][i][j] = bfbits(exp2f(acc[ri][i][j]));
#pragma unroll
    for (int i = 0; i < 4; ++i) {
      int kc = qtr * 4 + i;
      bf16x4 vf0 = *(const bf16x4*)&Vt[lq][kc * 16 + lg * 4];
      bf16x4 vf1 = *(const bf16x4*)&Vt[16 + lq][kc * 16 + lg * 4];
#pragma unroll
      for (int ri = 0; ri < 2; ++ri) {
        U[ri][0] = MFMA16(af[ri][i], vf0, U[ri][0], 0, 0, 0);
        U[ri][1] = MFMA16(af[ri][i], vf1, U[ri][1], 0, 0, 0);
        L[ri]    = MFMA16(af[ri][i], ones, L[ri], 0, 0, 0);
        BV[ri][0] = MFMA16(bfr[ri][i], vf0, BV[ri][0], 0, 0, 0);
        BV[ri][1] = MFMA16(bfr[ri][i], vf1, BV[ri][1], 0, 0, 0);
      }
    }
  }

  __syncthreads();  // done reading Ks; reuse as Res

  // results -> LDS bf16 [256 rows][32 cols]
#pragma unroll
  for (int ri = 0; ri < 2; ++ri) {
    f32x4 inv;
#pragma unroll
    for (int j = 0; j < 4; ++j) inv[j] = __builtin_amdgcn_rcpf(L[ri][j]);
#pragma unroll
    for (int ct = 0; ct < 2; ++ct) {
#pragma unroll
      for (int j = 0; j < 4; ++j) {
        int rl = rbase + ri * 16 + lg * 4 + j;
        Res[rl * 32 + ct * 16 + lq] =
            bfbits(U[ri][ct][j] * inv[j] + BV[ri][ct][j]);
      }
    }
  }
  __syncthreads();

  // coalesced epilogue: gate multiply + 16B stores
  {
    int row = t & 255, hf = t >> 8;
    size_t o = ((size_t)(s * 256 + row)) * 256 + h * 32 + hf * 16;
    bf16x8 r0 = *(const bf16x8*)&Res[row * 32 + hf * 16];
    bf16x8 r1 = *(const bf16x8*)&Res[row * 32 + hf * 16 + 8];
    bf16x8 g0 = *(const bf16x8*)&gate_bf[o];
    bf16x8 g1 = *(const bf16x8*)&gate_bf[o + 8];
    bf16x8 o0, o1;
#pragma unroll
    for (int i = 0; i < 8; ++i) {
      o0[i] = bfbits(bf2f((unsigned short)r0[i]) * bf2f((unsigned short)g0[i]));
      o1[i] = bfbits(bf2f((unsigned short)r1[i]) * bf2f((unsigned short)g1[i]));
    }
    *(bf16x8*)&attn_bf[o] = o0;
    *(bf16x8*)&attn_bf[o + 8] = o1;
  }
}

// ---------------------------------------------------------------------------
// gemm_out: attn_bf[32768,256] @ Woutt^T -> out f32
// ---------------------------------------------------------------------------
__global__ __launch_bounds__(256) void gemm_out2(
    const short* __restrict__ A, const short* __restrict__ Wt,
    float* __restrict__ out) {
  __shared__ short As2[2][128 * 64];
  __shared__ short Bs2[2][128 * 64];
  int t = threadIdx.x;
  int lane = t & 63, wid = t >> 6;
  int lq = lane & 15, lg = lane >> 4;
  int wm = wid >> 1, wn = wid & 1;
  int r0 = blockIdx.x * 128, n0 = blockIdx.y * 128;

  auto stage = [&](int s, int buf) {
#pragma unroll
    for (int q = 0; q < 4; ++q) {
      int P = wid * 4096 + q * 1024 + lane * 16;
      int row = P >> 7, kb = P & 127;
      int klog = kb ^ ((row & 7) << 4);
      gll16((const char*)A + ((size_t)(r0 + row) * 512 + s * 128 + klog),
            (char*)&As2[buf][0] + wid * 4096 + q * 1024);
      gll16((const char*)Wt + ((size_t)(n0 + row) * 512 + s * 128 + klog),
            (char*)&Bs2[buf][0] + wid * 4096 + q * 1024);
    }
  };

  f32x4 acc[4][4];
#pragma unroll
  for (int a = 0; a < 4; ++a)
#pragma unroll
    for (int b = 0; b < 4; ++b) acc[a][b] = {0.f, 0.f, 0.f, 0.f};

  stage(0, 0);
  __syncthreads();
  for (int s = 0; s < 4; ++s) {
    if (s < 3) stage(s + 1, (s + 1) & 1);
    bf16x8 afr[4][2], bfr[4][2];
#pragma unroll
    for (int kcl = 0; kcl < 2; ++kcl) {
#pragma unroll
      for (int mf = 0; mf < 4; ++mf) {
        int row = wm * 64 + mf * 16 + lq;
        int kb = (((kcl << 6) | (lg << 4))) ^ ((row & 7) << 4);
        afr[mf][kcl] = *(const bf16x8*)((const char*)&As2[s & 1][0] + row * 128 + kb);
      }
#pragma unroll
      for (int nf = 0; nf < 4; ++nf) {
        int col = wn * 64 + nf * 16 + lq;
        int kb = (((kcl << 6) | (lg << 4))) ^ ((col & 7) << 4);
        bfr[nf][kcl] = *(const bf16x8*)((const char*)&Bs2[s & 1][0] + col * 128 + kb);
      }
    }
#pragma unroll
    for (int mf = 0; mf < 4; ++mf)
#pragma unroll
      for (int nf = 0; nf < 4; ++nf)
#pragma unroll
        for (int kcl = 0; kcl < 2; ++kcl)
          acc[mf][nf] = MFMA32(afr[mf][kcl], bfr[nf][kcl], acc[mf][nf], 0, 0, 0);
    __syncthreads();
  }
#pragma unroll
  for (int mf = 0; mf < 4; ++mf)
#pragma unroll
    for (int nf = 0; nf < 4; ++nf) {
      int col = n0 + wn * 64 + nf * 16 + lq;
#pragma unroll
      for (int j = 0; j < 4; ++j) {
        int row = r0 + wm * 64 + mf * 16 + lg * 4 + j;
        out[(size_t)row * 256 + col] = acc[mf][nf][j];
      }
    }
}

// ---------------------------------------------------------------------------
extern "C" void kernel_launch(void* const* d_in, const int* in_sizes, int n_in,
                              void* d_out, int out_size, void* d_ws,
                              size_t ws_size, hipStream_t stream) {
  const float* msa  = (const float*)d_in[0];
  const float* pair = (const float*)d_in[1];
  const float* Wg   = (const float*)d_in[2];
  const float* Wqkv = (const float*)d_in[3];
  const float* Wout = (const float*)d_in[4];
  const float* Bp   = (const float*)d_in[5];
  float* out = (float*)d_out;
  short* sw = (short*)d_ws;

  short* bias_bf = sw;                 //   524288 shorts
  short* gate_bf = sw + 524288;        //  8388608
  short* qkv_bf  = sw + 8912896;       // 25165824
  short* attn_bf = sw + 34078720;      //  8388608
  short* Wt_bf   = sw + 42467328;      //   262144
  short* Woutt   = sw + 42729472;      //    65536

  hipLaunchKernelGGL(wconv_kernel, dim3(1280), dim3(256), 0, stream,
                     Wg, Wqkv, Wout, Wt_bf, Woutt);
  hipLaunchKernelGGL(bias_kernel, dim3(256), dim3(256), 0, stream,
                     pair, Bp, bias_bf);
  hipLaunchKernelGGL(gemm_fused, dim3(256), dim3(512), 0, stream,
                     msa, Wt_bf, gate_bf, qkv_bf);
  hipLaunchKernelGGL(attn_mfma3, dim3(128, 8), dim3(512), 0, stream,
                     qkv_bf, bias_bf, gate_bf, attn_bf);
  hipLaunchKernelGGL(gemm_out2, dim3(256, 2), dim3(256), 0, stream,
                     attn_bf, Woutt, out);
}

// Round 6
// 96.189 us; speedup vs baseline: 6.8043x; 1.1108x over previous
//
#include <hip/hip_runtime.h>
#include <hip/hip_bf16.h>
#include <math.h>

typedef __attribute__((ext_vector_type(8))) short bf16x8;
typedef __attribute__((ext_vector_type(4))) short bf16x4;
typedef __attribute__((ext_vector_type(4))) float f32x4;

#define MFMA32 __builtin_amdgcn_mfma_f32_16x16x32_bf16
#define MFMA16 __builtin_amdgcn_mfma_f32_16x16x16bf16_1k

#define QSCALE 0.25503485964546277f  // (1/sqrt(32)) * log2(e)

__device__ inline short bfbits(float f) {
  union { float f; unsigned u; } v; v.f = f;
  unsigned r = v.u + 0x7fffu + ((v.u >> 16) & 1u);
  return (short)(r >> 16);
}
__device__ inline float bf2f(unsigned short u) {
  union { unsigned u; float f; } v; v.u = ((unsigned)u) << 16; return v.f;
}
__device__ inline void gll16(const void* g, void* l) {
  __builtin_amdgcn_global_load_lds(
      (const __attribute__((address_space(1))) unsigned*)g,
      (__attribute__((address_space(3))) unsigned*)l, 16, 0, 0);
}
// pack 4 f32 -> bf16x4 via v_cvt_pk_bf16_f32 (RTNE)
__device__ inline bf16x4 pk4(float e0, float e1, float e2, float e3) {
  unsigned lo, hi;
  asm("v_cvt_pk_bf16_f32 %0, %1, %2" : "=v"(lo) : "v"(e0), "v"(e1));
  asm("v_cvt_pk_bf16_f32 %0, %1, %2" : "=v"(hi) : "v"(e2), "v"(e3));
  union { unsigned u[2]; bf16x4 v; } cv;
  cv.u[0] = lo; cv.u[1] = hi;
  return cv.v;
}

// ---------------------------------------------------------------------------
// wconv: Wt[col][k] bf16 (cols 0..255 gate, 256..1023 qkv w/ q-cols pre-scaled
// by QSCALE); Woutt[col][k] bf16.
// ---------------------------------------------------------------------------
__global__ __launch_bounds__(256) void wconv_kernel(
    const float* __restrict__ Wg, const float* __restrict__ Wqkv,
    const float* __restrict__ Wout, short* __restrict__ Wt,
    short* __restrict__ Woutt) {
  int idx = blockIdx.x * 256 + threadIdx.x;
  if (idx < 1024 * 256) {
    int col = idx >> 8, k = idx & 255;
    float v;
    if (col < 256) {
      v = Wg[k * 256 + col];
    } else {
      int wc = col - 256;
      v = Wqkv[k * 768 + wc];
      if ((wc % 96) < 32) v *= QSCALE;
    }
    Wt[idx] = bfbits(v);
  } else {
    int j = idx - 1024 * 256;
    int col = j >> 8, k = j & 255;
    Woutt[j] = bfbits(Wout[k * 256 + col]);
  }
}

// ---------------------------------------------------------------------------
// bias_bf[h][r][p] = bf16( sum_z pair[r][p][z] * bproj[z][h] )
// ---------------------------------------------------------------------------
__global__ __launch_bounds__(256) void bias_kernel(
    const float* __restrict__ pair, const float* __restrict__ bproj,
    short* __restrict__ bias_bf) {
  __shared__ float bp[128 * 8];
  int t = threadIdx.x;
  for (int i = t; i < 128 * 8; i += 256) bp[i] = bproj[i];
  __syncthreads();
  int idx = blockIdx.x * 256 + t;
  const float4* src = (const float4*)(pair + (size_t)idx * 128);
  float acc[8] = {};
#pragma unroll
  for (int z4 = 0; z4 < 32; ++z4) {
    float4 v = src[z4];
    const float* b0 = &bp[z4 * 32];
#pragma unroll
    for (int h = 0; h < 8; ++h) {
      acc[h] += v.x * b0[h] + v.y * b0[8 + h] +
                v.z * b0[16 + h] + v.w * b0[24 + h];
    }
  }
#pragma unroll
  for (int h = 0; h < 8; ++h)
    bias_bf[(size_t)h * 65536 + idx] = bfbits(acc[h]);
}

// ---------------------------------------------------------------------------
// gemm_fused: X[32768,256]f32 @ Wt^T[256,1024] -> gate(sigmoid,bf16) | qkv(bf16)
// ---------------------------------------------------------------------------
__global__ __launch_bounds__(512) void gemm_fused(
    const float* __restrict__ X, const short* __restrict__ Wt,
    short* __restrict__ gate_bf, short* __restrict__ qkv_bf) {
  __shared__ short As[128 * 256];      // 64KB
  __shared__ short Bs[2][256 * 64];    // 2 x 32KB
  int t = threadIdx.x;
  int lane = t & 63, wid = t >> 6;
  int lq = lane & 15, lg = lane >> 4;
  int wm = wid >> 2, wn = wid & 3;
  int r0 = blockIdx.x * 128;

  {
    int row = t >> 2;
    int kb = (t & 3) * 64;
    const float* xrow = &X[(size_t)(r0 + row) * 256 + kb];
    int swz = (row & 7) << 4;
#pragma unroll
    for (int q = 0; q < 8; ++q) {
      float4 va = *(const float4*)(xrow + q * 8);
      float4 vb = *(const float4*)(xrow + q * 8 + 4);
      bf16x8 o = {bfbits(va.x), bfbits(va.y), bfbits(va.z), bfbits(va.w),
                  bfbits(vb.x), bfbits(vb.y), bfbits(vb.z), bfbits(vb.w)};
      int kbyte = kb * 2 + q * 16;
      *(bf16x8*)((char*)As + row * 512 + (kbyte ^ swz)) = o;
    }
  }

  auto stage = [&](int step, int buf) {
    int nt2 = step >> 2, k642 = step & 3;
#pragma unroll
    for (int q = 0; q < 4; ++q) {
      int P = wid * 4096 + q * 1024 + lane * 16;
      int col = P >> 7, kb = P & 127;
      int klog = kb ^ ((col & 7) << 4);
      gll16((const char*)Wt + ((size_t)(nt2 * 256 + col) * 512 + k642 * 128 + klog),
            (char*)&Bs[buf][0] + wid * 4096 + q * 1024);
    }
  };

  f32x4 acc[4][4];
#pragma unroll
  for (int a = 0; a < 4; ++a)
#pragma unroll
    for (int b = 0; b < 4; ++b) acc[a][b] = {0.f, 0.f, 0.f, 0.f};

  stage(0, 0);
  __syncthreads();

  for (int s = 0; s < 16; ++s) {
    int ntile = s >> 2, k64 = s & 3;
    if (s < 15) stage(s + 1, (s + 1) & 1);
    const char* bbase = (const char*)&Bs[s & 1][0];
    bf16x8 afr[4][2], bfr[4][2];
#pragma unroll
    for (int kcl = 0; kcl < 2; ++kcl) {
#pragma unroll
      for (int mf = 0; mf < 4; ++mf) {
        int row = wm * 64 + mf * 16 + lq;
        int kbyte = k64 * 128 + ((((kcl << 6) | (lg << 4))) ^ ((row & 7) << 4));
        afr[mf][kcl] = *(const bf16x8*)((const char*)As + row * 512 + kbyte);
      }
#pragma unroll
      for (int nf = 0; nf < 4; ++nf) {
        int col = wn * 64 + nf * 16 + lq;
        int kbyte = (((kcl << 6) | (lg << 4))) ^ ((col & 7) << 4);
        bfr[nf][kcl] = *(const bf16x8*)(bbase + col * 128 + kbyte);
      }
    }
#pragma unroll
    for (int mf = 0; mf < 4; ++mf)
#pragma unroll
      for (int nf = 0; nf < 4; ++nf)
#pragma unroll
        for (int kcl = 0; kcl < 2; ++kcl)
          acc[mf][nf] = MFMA32(afr[mf][kcl], bfr[nf][kcl], acc[mf][nf], 0, 0, 0);
    __syncthreads();

    if (k64 == 3) {
      if (ntile == 0) {
#pragma unroll
        for (int mf = 0; mf < 4; ++mf)
#pragma unroll
          for (int nf = 0; nf < 4; ++nf) {
            int col = wn * 64 + nf * 16 + lq;
#pragma unroll
            for (int j = 0; j < 4; ++j) {
              int row = r0 + wm * 64 + mf * 16 + lg * 4 + j;
              float v = acc[mf][nf][j];
              float sg = __builtin_amdgcn_rcpf(1.f + __expf(-v));
              gate_bf[(size_t)row * 256 + col] = bfbits(sg);
            }
          }
      } else {
        int cb = ntile * 256 - 256;
#pragma unroll
        for (int mf = 0; mf < 4; ++mf)
#pragma unroll
          for (int nf = 0; nf < 4; ++nf) {
            int col = cb + wn * 64 + nf * 16 + lq;
#pragma unroll
            for (int j = 0; j < 4; ++j) {
              int row = r0 + wm * 64 + mf * 16 + lg * 4 + j;
              qkv_bf[(size_t)row * 768 + col] = bfbits(acc[mf][nf][j]);
            }
          }
      }
#pragma unroll
      for (int a = 0; a < 4; ++a)
#pragma unroll
        for (int b = 0; b < 4; ++b) acc[a][b] = {0.f, 0.f, 0.f, 0.f};
    }
  }
}

// ---------------------------------------------------------------------------
// attn v4: one block per (s,h), 512 thr (8 waves x 32 rows).
// K in LDS (gll16, slot-swizzled); V^T in LDS.
// simT = K@Q^T; E = exp2(simT) via v_exp + v_cvt_pk_bf16_f32;
// attend = (E@V)*rcp(E@1) + bias@V (bias@V via 16x16x32 MFMA, contiguous
// 16B bias frags); epilogue via LDS bounce, coalesced gate-mul + store.
// ---------------------------------------------------------------------------
__global__ __launch_bounds__(512, 4) void attn_mfma4(
    const short* __restrict__ qkv, const short* __restrict__ bias_bf,
    const short* __restrict__ gate_bf, short* __restrict__ attn_bf) {
  int s = blockIdx.x, h = blockIdx.y;
  __shared__ short Ks[8192];       // [256 p][4 slots of 16B], slot-swizzled
  __shared__ short Vt[32][260];    // V^T [c][p]
  short* Res = Ks;                 // reused after PV (barrier-protected)
  int t = threadIdx.x;
  int lane = t & 63, wid = t >> 6;
  int lq = lane & 15, lg = lane >> 4;
  const short* qkv_s = qkv + (size_t)s * 196608 + h * 96;

  // stage K: LDS linear dest, pre-swizzled global source (slot^((p>>1)&3))
#pragma unroll
  for (int q = 0; q < 2; ++q) {
    int off = wid * 2048 + q * 1024 + lane * 16;  // byte offset in Ks
    int p = off >> 6;
    int slot = (off >> 4) & 3;
    int cg = slot ^ ((p >> 1) & 3);
    gll16(qkv_s + p * 768 + 32 + cg * 8, (char*)Ks + wid * 2048 + q * 1024);
  }
  // stage V^T (register transpose)
  {
    int p = t >> 1, hf = t & 1;
    const short* src = qkv_s + p * 768 + 64 + hf * 16;
    bf16x8 v0 = *(const bf16x8*)src;
    bf16x8 v1 = *(const bf16x8*)(src + 8);
#pragma unroll
    for (int i = 0; i < 8; ++i) {
      Vt[hf * 16 + i][p] = v0[i];
      Vt[hf * 16 + 8 + i][p] = v1[i];
    }
  }

  int rbase = wid * 32;
  bf16x8 qf0 = *(const bf16x8*)(qkv_s + (size_t)(rbase + lq) * 768 + lg * 8);
  bf16x8 qf1 = *(const bf16x8*)(qkv_s + (size_t)(rbase + 16 + lq) * 768 + lg * 8);
  const short* bb0 =
      bias_bf + ((size_t)h * 256 + rbase + lq) * 256 + lg * 8;  // 16B frags
  const short* bb1 = bb0 + 16 * 256;

  f32x4 U[2][2], BV[2][2], L[2];
#pragma unroll
  for (int ri = 0; ri < 2; ++ri) {
    L[ri] = {0.f, 0.f, 0.f, 0.f};
#pragma unroll
    for (int ct = 0; ct < 2; ++ct) {
      U[ri][ct] = {0.f, 0.f, 0.f, 0.f};
      BV[ri][ct] = {0.f, 0.f, 0.f, 0.f};
    }
  }
  const bf16x4 ones = {16256, 16256, 16256, 16256};  // bf16 1.0

  __syncthreads();

#pragma unroll
  for (int qtr = 0; qtr < 4; ++qtr) {
    // K fragments (LDS) + bias fragments (global, 16B contiguous)
    bf16x8 kf[4];
    bf16x8 bfa[2][2];  // [chunk][ri]
#pragma unroll
    for (int i = 0; i < 4; ++i) {
      int row = (qtr * 4 + i) * 16 + lq;
      kf[i] = *(const bf16x8*)((const char*)Ks + row * 64 +
                               ((lg ^ ((row >> 1) & 3)) << 4));
    }
#pragma unroll
    for (int c2 = 0; c2 < 2; ++c2) {
      int chunk = qtr * 2 + c2;
      bfa[c2][0] = *(const bf16x8*)(bb0 + chunk * 32);
      bfa[c2][1] = *(const bf16x8*)(bb1 + chunk * 32);
    }

    // QK^T
    f32x4 acc[2][4];
#pragma unroll
    for (int ri = 0; ri < 2; ++ri)
#pragma unroll
      for (int i = 0; i < 4; ++i) acc[ri][i] = {0.f, 0.f, 0.f, 0.f};
    __builtin_amdgcn_s_setprio(1);
#pragma unroll
    for (int i = 0; i < 4; ++i) {
      acc[0][i] = MFMA32(kf[i], qf0, acc[0][i], 0, 0, 0);
      acc[1][i] = MFMA32(kf[i], qf1, acc[1][i], 0, 0, 0);
    }
    // bias@V (independent of QK/exp — fills MFMA pipe under the exp burst)
#pragma unroll
    for (int c2 = 0; c2 < 2; ++c2) {
      int chunk = qtr * 2 + c2;
      bf16x8 v0 = *(const bf16x8*)&Vt[lq][chunk * 32 + lg * 8];
      bf16x8 v1 = *(const bf16x8*)&Vt[16 + lq][chunk * 32 + lg * 8];
      BV[0][0] = MFMA32(bfa[c2][0], v0, BV[0][0], 0, 0, 0);
      BV[0][1] = MFMA32(bfa[c2][0], v1, BV[0][1], 0, 0, 0);
      BV[1][0] = MFMA32(bfa[c2][1], v0, BV[1][0], 0, 0, 0);
      BV[1][1] = MFMA32(bfa[c2][1], v1, BV[1][1], 0, 0, 0);
    }
    __builtin_amdgcn_s_setprio(0);

    // E = exp2(sim); pack to bf16 A-frags via v_cvt_pk
    bf16x4 af[2][4];
#pragma unroll
    for (int ri = 0; ri < 2; ++ri)
#pragma unroll
      for (int i = 0; i < 4; ++i)
        af[ri][i] = pk4(__builtin_amdgcn_exp2f(acc[ri][i][0]),
                        __builtin_amdgcn_exp2f(acc[ri][i][1]),
                        __builtin_amdgcn_exp2f(acc[ri][i][2]),
                        __builtin_amdgcn_exp2f(acc[ri][i][3]));

    // U = E@V, L = E@1
    __builtin_amdgcn_s_setprio(1);
#pragma unroll
    for (int i = 0; i < 4; ++i) {
      int kc = qtr * 4 + i;
      bf16x4 vf0 = *(const bf16x4*)&Vt[lq][kc * 16 + lg * 4];
      bf16x4 vf1 = *(const bf16x4*)&Vt[16 + lq][kc * 16 + lg * 4];
#pragma unroll
      for (int ri = 0; ri < 2; ++ri) {
        U[ri][0] = MFMA16(af[ri][i], vf0, U[ri][0], 0, 0, 0);
        U[ri][1] = MFMA16(af[ri][i], vf1, U[ri][1], 0, 0, 0);
        L[ri]    = MFMA16(af[ri][i], ones, L[ri], 0, 0, 0);
      }
    }
    __builtin_amdgcn_s_setprio(0);
  }

  __syncthreads();  // done reading Ks/Vt; reuse Ks as Res

  // results -> LDS bf16 [256 rows][32 cols]
#pragma unroll
  for (int ri = 0; ri < 2; ++ri) {
    f32x4 inv;
#pragma unroll
    for (int j = 0; j < 4; ++j) inv[j] = __builtin_amdgcn_rcpf(L[ri][j]);
#pragma unroll
    for (int ct = 0; ct < 2; ++ct) {
#pragma unroll
      for (int j = 0; j < 4; ++j) {
        int rl = rbase + ri * 16 + lg * 4 + j;
        Res[rl * 32 + ct * 16 + lq] =
            bfbits(U[ri][ct][j] * inv[j] + BV[ri][ct][j]);
      }
    }
  }
  __syncthreads();

  // coalesced epilogue: gate multiply + 16B stores
  {
    int row = t & 255, hf = t >> 8;
    size_t o = ((size_t)(s * 256 + row)) * 256 + h * 32 + hf * 16;
    bf16x8 r0 = *(const bf16x8*)&Res[row * 32 + hf * 16];
    bf16x8 r1 = *(const bf16x8*)&Res[row * 32 + hf * 16 + 8];
    bf16x8 g0 = *(const bf16x8*)&gate_bf[o];
    bf16x8 g1 = *(const bf16x8*)&gate_bf[o + 8];
    bf16x8 o0, o1;
#pragma unroll
    for (int i = 0; i < 8; ++i) {
      o0[i] = bfbits(bf2f((unsigned short)r0[i]) * bf2f((unsigned short)g0[i]));
      o1[i] = bfbits(bf2f((unsigned short)r1[i]) * bf2f((unsigned short)g1[i]));
    }
    *(bf16x8*)&attn_bf[o] = o0;
    *(bf16x8*)&attn_bf[o + 8] = o1;
  }
}

// ---------------------------------------------------------------------------
// gemm_out: attn_bf[32768,256] @ Woutt^T -> out f32
// ---------------------------------------------------------------------------
__global__ __launch_bounds__(256) void gemm_out2(
    const short* __restrict__ A, const short* __restrict__ Wt,
    float* __restrict__ out) {
  __shared__ short As2[2][128 * 64];
  __shared__ short Bs2[2][128 * 64];
  int t = threadIdx.x;
  int lane = t & 63, wid = t >> 6;
  int lq = lane & 15, lg = lane >> 4;
  int wm = wid >> 1, wn = wid & 1;
  int r0 = blockIdx.x * 128, n0 = blockIdx.y * 128;

  auto stage = [&](int s, int buf) {
#pragma unroll
    for (int q = 0; q < 4; ++q) {
      int P = wid * 4096 + q * 1024 + lane * 16;
      int row = P >> 7, kb = P & 127;
      int klog = kb ^ ((row & 7) << 4);
      gll16((const char*)A + ((size_t)(r0 + row) * 512 + s * 128 + klog),
            (char*)&As2[buf][0] + wid * 4096 + q * 1024);
      gll16((const char*)Wt + ((size_t)(n0 + row) * 512 + s * 128 + klog),
            (char*)&Bs2[buf][0] + wid * 4096 + q * 1024);
    }
  };

  f32x4 acc[4][4];
#pragma unroll
  for (int a = 0; a < 4; ++a)
#pragma unroll
    for (int b = 0; b < 4; ++b) acc[a][b] = {0.f, 0.f, 0.f, 0.f};

  stage(0, 0);
  __syncthreads();
  for (int s = 0; s < 4; ++s) {
    if (s < 3) stage(s + 1, (s + 1) & 1);
    bf16x8 afr[4][2], bfr[4][2];
#pragma unroll
    for (int kcl = 0; kcl < 2; ++kcl) {
#pragma unroll
      for (int mf = 0; mf < 4; ++mf) {
        int row = wm * 64 + mf * 16 + lq;
        int kb = (((kcl << 6) | (lg << 4))) ^ ((row & 7) << 4);
        afr[mf][kcl] = *(const bf16x8*)((const char*)&As2[s & 1][0] + row * 128 + kb);
      }
#pragma unroll
      for (int nf = 0; nf < 4; ++nf) {
        int col = wn * 64 + nf * 16 + lq;
        int kb = (((kcl << 6) | (lg << 4))) ^ ((col & 7) << 4);
        bfr[nf][kcl] = *(const bf16x8*)((const char*)&Bs2[s & 1][0] + col * 128 + kb);
      }
    }
#pragma unroll
    for (int mf = 0; mf < 4; ++mf)
#pragma unroll
      for (int nf = 0; nf < 4; ++nf)
#pragma unroll
        for (int kcl = 0; kcl < 2; ++kcl)
          acc[mf][nf] = MFMA32(afr[mf][kcl], bfr[nf][kcl], acc[mf][nf], 0, 0, 0);
    __syncthreads();
  }
#pragma unroll
  for (int mf = 0; mf < 4; ++mf)
#pragma unroll
    for (int nf = 0; nf < 4; ++nf) {
      int col = n0 + wn * 64 + nf * 16 + lq;
#pragma unroll
      for (int j = 0; j < 4; ++j) {
        int row = r0 + wm * 64 + mf * 16 + lg * 4 + j;
        out[(size_t)row * 256 + col] = acc[mf][nf][j];
      }
    }
}

// ---------------------------------------------------------------------------
extern "C" void kernel_launch(void* const* d_in, const int* in_sizes, int n_in,
                              void* d_out, int out_size, void* d_ws,
                              size_t ws_size, hipStream_t stream) {
  const float* msa  = (const float*)d_in[0];
  const float* pair = (const float*)d_in[1];
  const float* Wg   = (const float*)d_in[2];
  const float* Wqkv = (const float*)d_in[3];
  const float* Wout = (const float*)d_in[4];
  const float* Bp   = (const float*)d_in[5];
  float* out = (float*)d_out;
  short* sw = (short*)d_ws;

  short* bias_bf = sw;                 //   524288 shorts
  short* gate_bf = sw + 524288;        //  8388608
  short* qkv_bf  = sw + 8912896;       // 25165824
  short* attn_bf = sw + 34078720;      //  8388608
  short* Wt_bf   = sw + 42467328;      //   262144
  short* Woutt   = sw + 42729472;      //    65536

  hipLaunchKernelGGL(wconv_kernel, dim3(1280), dim3(256), 0, stream,
                     Wg, Wqkv, Wout, Wt_bf, Woutt);
  hipLaunchKernelGGL(bias_kernel, dim3(256), dim3(256), 0, stream,
                     pair, Bp, bias_bf);
  hipLaunchKernelGGL(gemm_fused, dim3(256), dim3(512), 0, stream,
                     msa, Wt_bf, gate_bf, qkv_bf);
  hipLaunchKernelGGL(attn_mfma4, dim3(128, 8), dim3(512), 0, stream,
                     qkv_bf, bias_bf, gate_bf, attn_bf);
  hipLaunchKernelGGL(gemm_out2, dim3(256, 2), dim3(256), 0, stream,
                     attn_bf, Woutt, out);
}